// Round 9
// baseline (104.888 us; speedup 1.0000x reference)
//
#include <hip/hip_runtime.h>
#include <hip/hip_fp16.h>

#define SEQ   80
#define BATCH 32768
#define HID   10

typedef unsigned int uint;
typedef unsigned short ushort;
typedef _Float16 f16;
typedef __attribute__((ext_vector_type(8))) _Float16 f16x8;
typedef __attribute__((ext_vector_type(2))) _Float16 f16x2;
typedef __attribute__((ext_vector_type(4))) float f32x4;

#define SIG_SCALE  (-1.44269504f)
#define TANH_SCALE (-2.88539008f)

__device__ __forceinline__ float fast_rcp(float x)  { return __builtin_amdgcn_rcpf(x); }
__device__ __forceinline__ float fast_exp2(float x) { return __builtin_amdgcn_exp2f(x); }
__device__ __forceinline__ float sigp(float a)  { return fast_rcp(1.0f + fast_exp2(a)); }
__device__ __forceinline__ float tanhp(float a) { return 2.0f * fast_rcp(1.0f + fast_exp2(a)) - 1.0f; }
__device__ __forceinline__ float tanh_f(float x){ return tanhp(TANH_SCALE * x); }

union U4V { uint4 u; f16x8 v; };
union UH2 { uint u; f16x2 h; };
union HU  { f16 h; ushort s; };

// Merged-rcp LSTM cell: 5 exp2 + 3 rcp.
__device__ __forceinline__ float lstm_unit(const f32x4 d, float& c) {
    const float Ei = fast_exp2(d[0]);
    const float Ef = fast_exp2(d[1]);
    const float Eg = fast_exp2(d[2]);
    const float Eo = fast_exp2(d[3]);
    const float Rf  = fast_rcp(1.0f + Ef);
    const float Rig = fast_rcp((1.0f + Ei) * (1.0f + Eg));
    c = c * Rf + (1.0f - Eg) * Rig;
    const float Ec = fast_exp2(TANH_SCALE * c);
    const float Rh = fast_rcp((1.0f + Eo) * (1.0f + Ec));
    return (1.0f - Ec) * Rh;
}

// Wave-specialized MFMA LSTM: per 16-batch group, wave role 0 runs layer 0 at
// step i, wave role 1 runs layer 1 at step i-1 (one-step lag). h state flows
// through triple-buffered LDS rows (write buf[i%3], read buf[(i-1)%3]; 3 bufs
// + 1 barrier/iter make the 1-iter skew race-free). 4096 waves (4/SIMD) at
// half the per-wave work of round 8 -> same pipe totals, 2x latency hiding
// (round 8: 2 waves/SIMD could not keep the trans pipe fed; VALUBusy 58%).
// Row layout (40 f16, 80 B for bank stagger): slots 0-9 h0, 10-19 h1, 20-31
// zero, so layer 1's B-operand is a raw ds_read_b128 and layer 0 masks/patches
// x exactly as before.
__global__ __launch_bounds__(256, 4)
void lstm2_spec(const float* __restrict__ x, const float* __restrict__ h0in,
                const float* __restrict__ c0in,
                const float* __restrict__ Wih0, const float* __restrict__ Whh0,
                const float* __restrict__ bih0, const float* __restrict__ bhh0,
                const float* __restrict__ Wih1, const float* __restrict__ Whh1,
                const float* __restrict__ bih1, const float* __restrict__ bhh1,
                ushort* __restrict__ y /* f16 bits of h1 (pre-tanh), [T,B,H] */) {
    __shared__ __align__(16) ushort buf[2][3][16][40];
    const int tid  = threadIdx.x;
    const int l    = tid & 63;
    const int wv   = tid >> 6;
    const int pair = wv >> 1;      // 0,1: two batch-16 groups per block
    const int role = wv & 1;       // 0: layer 0   1: layer 1
    const int bl   = l & 15;       // batch column
    const int grp  = l >> 4;       // row/k group
    const long b   = ((long)blockIdx.x * 2 + pair) * 16 + bl;

    // ---------- unified A fragment & bias (role-dependent source) ----------
    f16x8 A[3];
    f32x4 bs[3];
#pragma unroll
    for (int T = 0; T < 3; ++T) {
        const int R  = 16 * T + bl;
        const int u  = R >> 2, gi = R & 3;
        const bool vr = (R < 40);
        const int tr = gi * 10 + u;
        const float sc = (gi == 2) ? TANH_SCALE : SIG_SCALE;
#pragma unroll
        for (int j = 0; j < 8; ++j) {
            const int k = grp * 8 + j;
            float w = 0.f;
            if (vr) {
                if (role == 0) {
                    if (k < 10)      w = Whh0[tr * 10 + k];
                    else if (k < 12) w = Wih0[tr * 2 + (k - 10)];
                } else {
                    if (k < 10)      w = Wih1[tr * 10 + k];
                    else if (k < 20) w = Whh1[tr * 10 + (k - 10)];
                }
            }
            A[T][j] = (f16)(w * sc);
        }
#pragma unroll
        for (int q = 0; q < 4; ++q) {
            const int Rc = 16 * T + grp * 4 + q;
            const int uc = Rc >> 2, gc = Rc & 3;
            const float scc = (gc == 2) ? TANH_SCALE : SIG_SCALE;
            const int trc = gc * 10 + uc;
            float bb = 0.f;
            if (Rc < 40)
                bb = (role == 0) ? (bih0[trc] + bhh0[trc]) : (bih1[trc] + bhh1[trc]);
            bs[T][q] = bb * scc;
        }
    }

    // ---------- c state (this role's layer) ----------
    const size_t cbase = (role == 0) ? 0 : (size_t)BATCH * 10;
    float cS[3];
#pragma unroll
    for (int T = 0; T < 3; ++T) {
        const int u = 4 * T + grp;
        cS[T] = (u < 10) ? c0in[cbase + b * 10 + u] : 0.f;
    }

    // ---------- LDS init: zero all buffers ----------
    {
        uint* p = (uint*)buf;                    // 7680 B = 1920 uints
        for (int idx = tid; idx < 1920; idx += 256) p[idx] = 0u;
    }
    __syncthreads();
    // role 0 seeds h0(-1) into buf[2] (read at iter 0); role 1 seeds h1(-1)
    // into buf[0] (read at iter 1).
    if (role == 0) {
        ushort* row = &buf[pair][2][bl][0];
#pragma unroll
        for (int T = 0; T < 3; ++T) {
            const int u = 4 * T + grp;
            if (u < 10) { HU h; h.h = (f16)h0in[b * 10 + u]; row[u] = h.s; }
        }
    } else {
        ushort* row = &buf[pair][0][bl][0];
#pragma unroll
        for (int T = 0; T < 3; ++T) {
            const int u = 4 * T + grp;
            if (u < 10) { HU h; h.h = (f16)h0in[(size_t)BATCH * 10 + b * 10 + u]; row[10 + u] = h.s; }
        }
    }

    float2 xv = make_float2(0.f, 0.f);
    if (role == 0) xv = *reinterpret_cast<const float2*>(&x[b * 2]);

    for (int i = 0; i <= SEQ; ++i) {
        __syncthreads();
        const int wq = i % 3;
        const int rq = (i + 2) % 3;
        const ushort* rrow = &buf[pair][rq][bl][0];
        ushort* wrow = &buf[pair][wq][bl][0];

        if (role == 0) {
            if (i < SEQ) {
                const int tn = (i + 1 < SEQ) ? i + 1 : SEQ - 1;
                const float2 xnext = *reinterpret_cast<const float2*>(&x[((size_t)tn * BATCH + b) * 2]);

                U4V r; r.u = *reinterpret_cast<const uint4*>(rrow + grp * 8);
                UH2 xp; xp.h[0] = (f16)xv.x; xp.h[1] = (f16)xv.y;
                U4V bv;
                bv.u.x = (grp < 2)  ? r.u.x : 0u;
                bv.u.y = (grp == 0) ? r.u.y : ((grp == 1) ? xp.u : 0u);
                bv.u.z = (grp == 0) ? r.u.z : 0u;
                bv.u.w = (grp == 0) ? r.u.w : 0u;

                f32x4 d0 = __builtin_amdgcn_mfma_f32_16x16x32_f16(A[0], bv.v, bs[0], 0, 0, 0);
                f32x4 d1 = __builtin_amdgcn_mfma_f32_16x16x32_f16(A[1], bv.v, bs[1], 0, 0, 0);
                f32x4 d2 = __builtin_amdgcn_mfma_f32_16x16x32_f16(A[2], bv.v, bs[2], 0, 0, 0);

                HU hA; hA.h = (f16)lstm_unit(d0, cS[0]);
                HU hB; hB.h = (f16)lstm_unit(d1, cS[1]);
                HU hC; hC.h = (f16)lstm_unit(d2, cS[2]);

                wrow[grp] = hA.s;
                wrow[4 + grp] = hB.s;
                if (grp < 2) wrow[8 + grp] = hC.s;

                xv = xnext;
            }
        } else {
            if (i >= 1) {
                U4V r; r.u = *reinterpret_cast<const uint4*>(rrow + grp * 8);

                f32x4 d0 = __builtin_amdgcn_mfma_f32_16x16x32_f16(A[0], r.v, bs[0], 0, 0, 0);
                f32x4 d1 = __builtin_amdgcn_mfma_f32_16x16x32_f16(A[1], r.v, bs[1], 0, 0, 0);
                f32x4 d2 = __builtin_amdgcn_mfma_f32_16x16x32_f16(A[2], r.v, bs[2], 0, 0, 0);

                HU hA; hA.h = (f16)lstm_unit(d0, cS[0]);
                HU hB; hB.h = (f16)lstm_unit(d1, cS[1]);
                HU hC; hC.h = (f16)lstm_unit(d2, cS[2]);

                wrow[10 + grp] = hA.s;
                wrow[14 + grp] = hB.s;
                if (grp < 2) wrow[18 + grp] = hC.s;

                ushort* yp = y + (size_t)(i - 1) * BATCH * HID + b * HID;
                yp[grp] = hA.s;
                yp[4 + grp] = hB.s;
                if (grp < 2) yp[8 + grp] = hC.s;
            }
        }
    }
}

// Head as MFMA GEMM over tanh(y): D[o,16 batch] += A(W1 f16)[o,k]*B[k,n],
// 25 k-chunks of 32; tanh applied to the staged raw-h1 before the MFMA.
__global__ __launch_bounds__(256, 2)
void head_mfma(const ushort* __restrict__ yflat, /* f16 bits of h1, [32768][800] */
               const float* __restrict__ W1, const float* __restrict__ b1,
               const float* __restrict__ W2, const float* __restrict__ b2,
               float* __restrict__ out) {
    __shared__ float sbuf[4][16][12];
    const int tid = threadIdx.x;
    const int l   = tid & 63;
    const int wv  = tid >> 6;
    const int bl  = l & 15;
    const int grp = l >> 4;
    const long row = ((long)blockIdx.x * 4 + wv) * 16 + bl;

    const ushort* yrow = yflat + row * 800;
    const float* arow = W1 + (size_t)(bl < 10 ? bl : 9) * 800;

    f32x4 acc = {0.f, 0.f, 0.f, 0.f};
#pragma unroll 5
    for (int c = 0; c < 25; ++c) {
        U4V bv; bv.u = *reinterpret_cast<const uint4*>(yrow + c * 32 + grp * 8);
        f16x8 tv;
#pragma unroll
        for (int e = 0; e < 8; ++e)
            tv[e] = (f16)tanh_f((float)bv.v[e]);
        const float4 w0 = *reinterpret_cast<const float4*>(arow + c * 32 + grp * 8);
        const float4 w1 = *reinterpret_cast<const float4*>(arow + c * 32 + grp * 8 + 4);
        f16x8 af;
        af[0] = (f16)w0.x; af[1] = (f16)w0.y; af[2] = (f16)w0.z; af[3] = (f16)w0.w;
        af[4] = (f16)w1.x; af[5] = (f16)w1.y; af[6] = (f16)w1.z; af[7] = (f16)w1.w;
        acc = __builtin_amdgcn_mfma_f32_16x16x32_f16(af, tv, acc, 0, 0, 0);
    }

#pragma unroll
    for (int q = 0; q < 4; ++q) {
        const int o = grp * 4 + q;
        if (o < 10)
            sbuf[wv][bl][o] = sigp(SIG_SCALE * (acc[q] + b1[o]));
    }
    // wave-synchronous redistribution

    float s[10];
#pragma unroll
    for (int o = 0; o < 10; ++o) s[o] = sbuf[wv][bl][o];

    float* op = out + row * 40 + grp * 10;
#pragma unroll
    for (int jj = 0; jj < 10; ++jj) {
        const int j = grp * 10 + jj;
        float r = b2[j];
#pragma unroll
        for (int o = 0; o < 10; ++o) r += s[o] * W2[j * 10 + o];
        op[jj] = r;
    }
}

extern "C" void kernel_launch(void* const* d_in, const int* in_sizes, int n_in,
                              void* d_out, int out_size, void* d_ws, size_t ws_size,
                              hipStream_t stream) {
    const float* x    = (const float*)d_in[0];
    const float* h0   = (const float*)d_in[1];
    const float* c0   = (const float*)d_in[2];
    const float* Wih0 = (const float*)d_in[3];
    const float* Whh0 = (const float*)d_in[4];
    const float* bih0 = (const float*)d_in[5];
    const float* bhh0 = (const float*)d_in[6];
    const float* Wih1 = (const float*)d_in[7];
    const float* Whh1 = (const float*)d_in[8];
    const float* bih1 = (const float*)d_in[9];
    const float* bhh1 = (const float*)d_in[10];
    const float* W1   = (const float*)d_in[11];
    const float* b1   = (const float*)d_in[12];
    const float* W2   = (const float*)d_in[13];
    const float* b2   = (const float*)d_in[14];
    float* out = (float*)d_out;
    ushort* yws = (ushort*)d_ws;  // f16 staging (raw h1), 80*32768*10*2 B

    // 2 batch-16 groups per block, each with an L0 wave + L1 wave: 1024 blocks
    lstm2_spec<<<1024, 256, 0, stream>>>(x, h0, c0, Wih0, Whh0, bih0, bhh0,
                                         Wih1, Whh1, bih1, bhh1, yws);
    head_mfma<<<512, 256, 0, stream>>>(yws, W1, b1, W2, b2, out);
}

// Round 11
// 102.312 us; speedup vs baseline: 1.0252x; 1.0252x over previous
//
#include <hip/hip_runtime.h>
#include <hip/hip_fp16.h>

#define SEQ   80
#define BATCH 32768
#define HID   10

typedef unsigned int uint;
typedef unsigned short ushort;
typedef _Float16 f16;
typedef __attribute__((ext_vector_type(8))) _Float16 f16x8;
typedef __attribute__((ext_vector_type(2))) _Float16 f16x2;
typedef __attribute__((ext_vector_type(2))) __fp16 fp16x2;
typedef __attribute__((ext_vector_type(4))) float f32x4;

#define SIG_SCALE  (-1.44269504f)
#define TANH_SCALE (-2.88539008f)

__device__ __forceinline__ float fast_rcp(float x)  { return __builtin_amdgcn_rcpf(x); }
__device__ __forceinline__ float fast_exp2(float x) { return __builtin_amdgcn_exp2f(x); }
__device__ __forceinline__ float sigp(float a)  { return fast_rcp(1.0f + fast_exp2(a)); }
__device__ __forceinline__ float tanhp(float a) { return 2.0f * fast_rcp(1.0f + fast_exp2(a)) - 1.0f; }
__device__ __forceinline__ float tanh_f(float x){ return tanhp(TANH_SCALE * x); }

union U4V { uint4 u; f16x8 v; };
union UH2 { uint u; f16x2 h; fp16x2 p; };
union HU  { f16 h; ushort s; };

// Single-rcp-merged LSTM cell: 5 exp2 + 2 rcp = 7 trans (was 8).
// R = rcp(Pi*Pg*Pf):  f = Pi*Pg*R = 1/Pf;  i*g = (1-Eg)*Pf*R = (1-Eg)/(Pi*Pg).
// Safe: |pre-scaled gate| <= ~15 here, far from exp2 overflow at 127.
__device__ __forceinline__ float lstm_unit(const f32x4 d, float& c) {
    const float Ei = fast_exp2(d[0]);
    const float Ef = fast_exp2(d[1]);
    const float Eg = fast_exp2(d[2]);
    const float Eo = fast_exp2(d[3]);
    const float Pi = 1.0f + Ei, Pf = 1.0f + Ef, Pg = 1.0f + Eg;
    const float PiPg = Pi * Pg;
    const float R = fast_rcp(PiPg * Pf);
    c = c * (PiPg * R) + ((1.0f - Eg) * Pf) * R;
    const float Ec = fast_exp2(TANH_SCALE * c);
    const float R2 = fast_rcp((1.0f + Eo) * (1.0f + Ec));
    return (1.0f - Ec) * R2;
}

// Wave-specialized MFMA LSTM (round-9 structure), instruction-diet edition:
// - 128-thread blocks: wave 0 = layer 0 at step i, wave 1 = layer 1 at step
//   i-1, triple-buffered LDS rows + 1 barrier/iter.
// - x/y addressed by pointer bumping (uniform adds), not per-step 64b mads.
// - B-operand assembled with precomputed AND/OR masks + cvt_pkrtz for x.
// - mod-3 rotation unrolled so buffer indices are compile-time.
__global__ __launch_bounds__(128, 4)
void lstm2_spec(const float* __restrict__ x, const float* __restrict__ h0in,
                const float* __restrict__ c0in,
                const float* __restrict__ Wih0, const float* __restrict__ Whh0,
                const float* __restrict__ bih0, const float* __restrict__ bhh0,
                const float* __restrict__ Wih1, const float* __restrict__ Whh1,
                const float* __restrict__ bih1, const float* __restrict__ bhh1,
                ushort* __restrict__ y /* f16 bits of h1 (pre-tanh), [T,B,H] */) {
    __shared__ __align__(16) ushort buf[3][16][40];
    const int tid  = threadIdx.x;
    const int l    = tid & 63;
    const int role = tid >> 6;     // 0: layer 0   1: layer 1
    const int bl   = l & 15;       // batch column
    const int grp  = l >> 4;       // row/k group
    const long b   = (long)blockIdx.x * 16 + bl;

    // ---------- A fragment & bias (role-dependent source) ----------
    f16x8 A[3];
    f32x4 bs[3];
#pragma unroll
    for (int T = 0; T < 3; ++T) {
        const int R  = 16 * T + bl;
        const int u  = R >> 2, gi = R & 3;
        const bool vr = (R < 40);
        const int tr = gi * 10 + u;
        const float sc = (gi == 2) ? TANH_SCALE : SIG_SCALE;
#pragma unroll
        for (int j = 0; j < 8; ++j) {
            const int k = grp * 8 + j;
            float w = 0.f;
            if (vr) {
                if (role == 0) {
                    if (k < 10)      w = Whh0[tr * 10 + k];
                    else if (k < 12) w = Wih0[tr * 2 + (k - 10)];
                } else {
                    if (k < 10)      w = Wih1[tr * 10 + k];
                    else if (k < 20) w = Whh1[tr * 10 + (k - 10)];
                }
            }
            A[T][j] = (f16)(w * sc);
        }
#pragma unroll
        for (int q = 0; q < 4; ++q) {
            const int Rc = 16 * T + grp * 4 + q;
            const int uc = Rc >> 2, gc = Rc & 3;
            const float scc = (gc == 2) ? TANH_SCALE : SIG_SCALE;
            const int trc = gc * 10 + uc;
            float bb = 0.f;
            if (Rc < 40)
                bb = (role == 0) ? (bih0[trc] + bhh0[trc]) : (bih1[trc] + bhh1[trc]);
            bs[T][q] = bb * scc;
        }
    }

    // ---------- c state ----------
    const size_t cbase = (role == 0) ? 0 : (size_t)BATCH * 10;
    float cS[3];
#pragma unroll
    for (int T = 0; T < 3; ++T) {
        const int u = 4 * T + grp;
        cS[T] = (u < 10) ? c0in[cbase + b * 10 + u] : 0.f;
    }

    // ---------- LDS zero + state seed ----------
    {
        uint* p = (uint*)buf;                    // 3840 B = 960 uints
        for (int idx = tid; idx < 960; idx += 128) p[idx] = 0u;
    }
    __syncthreads();
    if (role == 0) {
        ushort* row = &buf[2][bl][0];            // read at iter 0
#pragma unroll
        for (int T = 0; T < 3; ++T) {
            const int u = 4 * T + grp;
            if (u < 10) { HU h; h.h = (f16)h0in[b * 10 + u]; row[u] = h.s; }
        }
    } else {
        ushort* row = &buf[0][bl][0];            // read at iter 1
#pragma unroll
        for (int T = 0; T < 3; ++T) {
            const int u = 4 * T + grp;
            if (u < 10) { HU h; h.h = (f16)h0in[(size_t)BATCH * 10 + b * 10 + u]; row[10 + u] = h.s; }
        }
    }

    // ---------- pointers & masks ----------
    const float* xq = x + b * 2 + (size_t)BATCH * 2;   // points at x(1)
    float2 xv = make_float2(0.f, 0.f);
    if (role == 0) xv = *reinterpret_cast<const float2*>(x + b * 2);  // x(0)
    ushort* yq = y + b * HID;

    const uint mx  = (grp < 2)  ? 0xFFFFFFFFu : 0u;
    const uint my0 = (grp == 0) ? 0xFFFFFFFFu : 0u;
    const uint sx  = (grp == 1) ? 0xFFFFFFFFu : 0u;

    auto body = [&](int i, ushort (*W)[40], const ushort (*Rb)[40]) {
        __syncthreads();
        if (role == 0) {
            if (i < SEQ) {
                const float2 xnext = *reinterpret_cast<const float2*>(xq);
                U4V r; r.u = *reinterpret_cast<const uint4*>(&Rb[bl][0] + grp * 8);
                UH2 xp; xp.p = __builtin_amdgcn_cvt_pkrtz(xv.x, xv.y);
                U4V bv;
                bv.u.x = r.u.x & mx;
                bv.u.y = (r.u.y & my0) | (xp.u & sx);
                bv.u.z = r.u.z & my0;
                bv.u.w = r.u.w & my0;

                const f32x4 d0 = __builtin_amdgcn_mfma_f32_16x16x32_f16(A[0], bv.v, bs[0], 0, 0, 0);
                const f32x4 d1 = __builtin_amdgcn_mfma_f32_16x16x32_f16(A[1], bv.v, bs[1], 0, 0, 0);
                const f32x4 d2 = __builtin_amdgcn_mfma_f32_16x16x32_f16(A[2], bv.v, bs[2], 0, 0, 0);

                HU hA; hA.h = (f16)lstm_unit(d0, cS[0]);
                HU hB; hB.h = (f16)lstm_unit(d1, cS[1]);
                HU hC; hC.h = (f16)lstm_unit(d2, cS[2]);

                ushort* wrow = &W[bl][0];
                wrow[grp]     = hA.s;
                wrow[4 + grp] = hB.s;
                if (grp < 2) wrow[8 + grp] = hC.s;

                xv = xnext;
                if (i + 2 < SEQ) xq += (size_t)BATCH * 2;
            }
        } else {
            if (i >= 1) {
                U4V r; r.u = *reinterpret_cast<const uint4*>(&Rb[bl][0] + grp * 8);

                const f32x4 d0 = __builtin_amdgcn_mfma_f32_16x16x32_f16(A[0], r.v, bs[0], 0, 0, 0);
                const f32x4 d1 = __builtin_amdgcn_mfma_f32_16x16x32_f16(A[1], r.v, bs[1], 0, 0, 0);
                const f32x4 d2 = __builtin_amdgcn_mfma_f32_16x16x32_f16(A[2], r.v, bs[2], 0, 0, 0);

                HU hA; hA.h = (f16)lstm_unit(d0, cS[0]);
                HU hB; hB.h = (f16)lstm_unit(d1, cS[1]);
                HU hC; hC.h = (f16)lstm_unit(d2, cS[2]);

                ushort* wrow = &W[bl][0];
                wrow[10 + grp] = hA.s;
                wrow[14 + grp] = hB.s;
                if (grp < 2) wrow[18 + grp] = hC.s;

                yq[grp]     = hA.s;
                yq[4 + grp] = hB.s;
                if (grp < 2) yq[8 + grp] = hC.s;
                yq += (size_t)BATCH * HID;
            }
        }
    };

    // 81 iterations = 27 exact mod-3 groups: (w,r) = (0,2),(1,0),(2,1)
    for (int i0 = 0; i0 < 81; i0 += 3) {
        body(i0 + 0, buf[0], buf[2]);
        body(i0 + 1, buf[1], buf[0]);
        body(i0 + 2, buf[2], buf[1]);
    }
}

// Head as MFMA GEMM over tanh(y): D[o,16 batch] += A(W1 f16)[o,k]*B[k,n],
// 25 k-chunks of 32; tanh applied to the staged raw-h1 before the MFMA.
__global__ __launch_bounds__(256, 2)
void head_mfma(const ushort* __restrict__ yflat, /* f16 bits of h1, [32768][800] */
               const float* __restrict__ W1, const float* __restrict__ b1,
               const float* __restrict__ W2, const float* __restrict__ b2,
               float* __restrict__ out) {
    __shared__ float sbuf[4][16][12];
    const int tid = threadIdx.x;
    const int l   = tid & 63;
    const int wv  = tid >> 6;
    const int bl  = l & 15;
    const int grp = l >> 4;
    const long row = ((long)blockIdx.x * 4 + wv) * 16 + bl;

    const ushort* yrow = yflat + row * 800;
    const float* arow = W1 + (size_t)(bl < 10 ? bl : 9) * 800;

    f32x4 acc = {0.f, 0.f, 0.f, 0.f};
#pragma unroll 5
    for (int c = 0; c < 25; ++c) {
        U4V bv; bv.u = *reinterpret_cast<const uint4*>(yrow + c * 32 + grp * 8);
        f16x8 tv;
#pragma unroll
        for (int e = 0; e < 8; ++e)
            tv[e] = (f16)tanh_f((float)bv.v[e]);
        const float4 w0 = *reinterpret_cast<const float4*>(arow + c * 32 + grp * 8);
        const float4 w1 = *reinterpret_cast<const float4*>(arow + c * 32 + grp * 8 + 4);
        f16x8 af;
        af[0] = (f16)w0.x; af[1] = (f16)w0.y; af[2] = (f16)w0.z; af[3] = (f16)w0.w;
        af[4] = (f16)w1.x; af[5] = (f16)w1.y; af[6] = (f16)w1.z; af[7] = (f16)w1.w;
        acc = __builtin_amdgcn_mfma_f32_16x16x32_f16(af, tv, acc, 0, 0, 0);
    }

#pragma unroll
    for (int q = 0; q < 4; ++q) {
        const int o = grp * 4 + q;
        if (o < 10)
            sbuf[wv][bl][o] = sigp(SIG_SCALE * (acc[q] + b1[o]));
    }
    // wave-synchronous redistribution

    float s[10];
#pragma unroll
    for (int o = 0; o < 10; ++o) s[o] = sbuf[wv][bl][o];

    float* op = out + row * 40 + grp * 10;
#pragma unroll
    for (int jj = 0; jj < 10; ++jj) {
        const int j = grp * 10 + jj;
        float r = b2[j];
#pragma unroll
        for (int o = 0; o < 10; ++o) r += s[o] * W2[j * 10 + o];
        op[jj] = r;
    }
}

extern "C" void kernel_launch(void* const* d_in, const int* in_sizes, int n_in,
                              void* d_out, int out_size, void* d_ws, size_t ws_size,
                              hipStream_t stream) {
    const float* x    = (const float*)d_in[0];
    const float* h0   = (const float*)d_in[1];
    const float* c0   = (const float*)d_in[2];
    const float* Wih0 = (const float*)d_in[3];
    const float* Whh0 = (const float*)d_in[4];
    const float* bih0 = (const float*)d_in[5];
    const float* bhh0 = (const float*)d_in[6];
    const float* Wih1 = (const float*)d_in[7];
    const float* Whh1 = (const float*)d_in[8];
    const float* bih1 = (const float*)d_in[9];
    const float* bhh1 = (const float*)d_in[10];
    const float* W1   = (const float*)d_in[11];
    const float* b1   = (const float*)d_in[12];
    const float* W2   = (const float*)d_in[13];
    const float* b2   = (const float*)d_in[14];
    float* out = (float*)d_out;
    ushort* yws = (ushort*)d_ws;  // f16 staging (raw h1), 80*32768*10*2 B

    // one batch-16 group per 128-thread block (L0 wave + L1 wave): 2048 blocks
    lstm2_spec<<<2048, 128, 0, stream>>>(x, h0, c0, Wih0, Whh0, bih0, bhh0,
                                         Wih1, Whh1, bih1, bhh1, yws);
    head_mfma<<<512, 256, 0, stream>>>(yws, W1, b1, W2, b2, out);
}